// Round 11
// baseline (187.406 us; speedup 1.0000x reference)
//
#include <hip/hip_runtime.h>
#include <hip/hip_bf16.h>

typedef __bf16 bf16_t;
typedef __attribute__((ext_vector_type(8))) __bf16 bf16x8;
typedef __attribute__((ext_vector_type(4))) float f32x4;

#define TREES 8192
#define ENC 128
#define HH 100
#define G3 300
#define GSTRIDE 304
#define BB 128
#define LL 64
#define OUTD 104
#define TPB_TREES 8

__device__ __forceinline__ float sigm(float x) { return 1.0f / (1.0f + __expf(-x)); }
__device__ __forceinline__ float tanh_f(float x) { return 2.0f / (1.0f + __expf(-2.0f * x)) - 1.0f; }
__device__ __forceinline__ float bflo(unsigned int u) { return __builtin_bit_cast(float, u << 16); }
__device__ __forceinline__ float bfhi(unsigned int u) { return __builtin_bit_cast(float, u & 0xffff0000u); }

// LDS barrier WITHOUT vmcnt drain: waits LDS ops only, leaves global prefetch in flight.
__device__ __forceinline__ void ldsbar() {
  asm volatile("s_waitcnt lgkmcnt(0)\n\ts_barrier" ::: "memory");
}

// subtree size of node n in the 64-node complete binary tree
__device__ __forceinline__ int subtree_size(int n) {
  int np1 = n + 1;
  int d = 31 - __clz(np1);
  return ((64 >> d) - 1) + (((np1 & (np1 - 1)) == 0) ? 1 : 0);
}

// ---------------- K0: weights->bf16 + emb->bf16 table (grid-stride) --------------------
__global__ __launch_bounds__(256) void k0_prep(const float* __restrict__ W_lin,
                                               const float* __restrict__ Wi_f,
                                               const float* __restrict__ Wi_b,
                                               const float* __restrict__ emb,
                                               bf16_t* __restrict__ Wbf,
                                               bf16_t* __restrict__ Wibf,
                                               bf16_t* __restrict__ embbf) {
  int i = blockIdx.x * 256 + threadIdx.x;      // 0..524287
#pragma unroll
  for (int r = 0; r < 4; ++r) {
    int e = i + r * 524288;
    if (e < 1600000) {                         // 50000*128/4 float4's
      float4 v = ((const float4*)emb)[e];
      ushort4 u;
      u.x = __builtin_bit_cast(unsigned short, (bf16_t)v.x);
      u.y = __builtin_bit_cast(unsigned short, (bf16_t)v.y);
      u.z = __builtin_bit_cast(unsigned short, (bf16_t)v.z);
      u.w = __builtin_bit_cast(unsigned short, (bf16_t)v.w);
      ((ushort4*)embbf)[e] = u;
    }
  }
  if (i < 128 * 128) Wbf[i] = (bf16_t)W_lin[i];
  if (i < 608 * 128) {
    int jg = i >> 7, k = i & 127;
    int dir = (jg >= GSTRIDE) ? 1 : 0;
    int j = jg - dir * GSTRIDE;
    float v = 0.0f;
    if (j < G3) v = dir ? Wi_b[j * 128 + k] : Wi_f[j * 128 + k];
    Wibf[i] = (bf16_t)v;
  }
}

// ---------------- K1 v8 (best-known): swizzled LDS, non-draining barriers,
//                  3-barrier register-chained tree-sum, cross-barrier prefetch. ---------
__global__ __launch_bounds__(256) void k1_tree(const int* __restrict__ tokens,
                                               const bf16_t* __restrict__ embbf,
                                               const bf16_t* __restrict__ Wbf,
                                               const float* __restrict__ b_lin,
                                               float* __restrict__ encodes) {
  __shared__ float s_[64][129];
  __shared__ float maxbuf[2][128];
  __shared__ float sb[128];
  int tid = threadIdx.x;
  int wave = tid >> 6;
  int lane = tid & 63;
  int ri = lane & 15;
  int kg = lane >> 4;
  int wm = wave >> 1;
  int wn = wave & 1;

  if (tid < 128) sb[tid] = b_lin[tid];

  bf16x8 bfr[4][4];
#pragma unroll
  for (int ks = 0; ks < 4; ++ks)
#pragma unroll
    for (int ni = 0; ni < 4; ++ni)
      bfr[ks][ni] = *(const bf16x8*)(Wbf + (size_t)((wn * 4 + ni) * 16 + ri) * 128 +
                                     ks * 32 + kg * 8);

  float szs[2][4];
#pragma unroll
  for (int mi = 0; mi < 2; ++mi)
#pragma unroll
    for (int rr = 0; rr < 4; ++rr)
      szs[mi][rr] = (float)subtree_size(wm * 32 + mi * 16 + kg * 4 + rr);

  int n = tid >> 2;
  int q = tid & 3;
  int c = tid >> 1;
  int half = tid & 1;
  int pc = (c & ~31) | ((((c >> 3) + (c >> 5)) & 3) << 3) | (c & 7);
  int tree0 = blockIdx.x * TPB_TREES;

  uint4 pre[4];
  {
    int tok = tokens[tree0 * 64 + n];
    const uint4* src = (const uint4*)(embbf + (size_t)tok * ENC) + q * 4;
#pragma unroll
    for (int i = 0; i < 4; ++i) pre[i] = src[i];
  }
  __syncthreads();

  for (int t = 0; t < TPB_TREES; ++t) {
    int tree = tree0 + t;

#pragma unroll
    for (int i = 0; i < 4; ++i) {
      uint4 p = pre[i];
      float4 f0 = {bflo(p.x), bfhi(p.x), bflo(p.y), bfhi(p.y)};
      float4 f1 = {bflo(p.z), bfhi(p.z), bflo(p.w), bfhi(p.w)};
      int col = q * 32 + (((i + q) & 3) << 3);
      *(float4*)&s_[n][col] = f0;
      *(float4*)&s_[n][col + 4] = f1;
    }

    if (t + 1 < TPB_TREES) {
      int tok = tokens[(tree + 1) * 64 + n];
      const uint4* src = (const uint4*)(embbf + (size_t)tok * ENC) + q * 4;
#pragma unroll
      for (int i = 0; i < 4; ++i) pre[i] = src[i];
    }
    ldsbar();

    if (half == 0) s_[31][pc] += s_[63][pc];
    {
      float r[8];
      int pb = 15 + half * 8;
#pragma unroll
      for (int i = 0; i < 8; ++i) {
        int p = pb + i;
        r[i] = s_[p][pc] + s_[2 * p + 1][pc] + s_[2 * p + 2][pc];
        s_[p][pc] = r[i];
      }
      float tt[4];
      int pb2 = 7 + half * 4;
#pragma unroll
      for (int i = 0; i < 4; ++i) {
        int p = pb2 + i;
        tt[i] = s_[p][pc] + r[2 * i] + r[2 * i + 1];
        s_[p][pc] = tt[i];
      }
      float uu[2];
      int pb3 = 3 + half * 2;
#pragma unroll
      for (int i = 0; i < 2; ++i) {
        int p = pb3 + i;
        uu[i] = s_[p][pc] + tt[2 * i] + tt[2 * i + 1];
        s_[p][pc] = uu[i];
      }
      int p1 = 1 + half;
      float w1 = s_[p1][pc] + uu[0] + uu[1];
      s_[p1][pc] = w1;
      float w2 = __shfl_xor(w1, 1);
      if (half == 0) s_[0][pc] = s_[0][pc] + w1 + w2;
    }
    ldsbar();

    f32x4 acc[2][4];
#pragma unroll
    for (int mi = 0; mi < 2; ++mi)
#pragma unroll
      for (int ni = 0; ni < 4; ++ni) {
        f32x4 z = {0.f, 0.f, 0.f, 0.f};
        acc[mi][ni] = z;
      }
#pragma unroll
    for (int ks = 0; ks < 4; ++ks) {
      int k0p = ks * 32 + (((kg + ks) & 3) << 3);
#pragma unroll
      for (int mi = 0; mi < 2; ++mi) {
        int row = wm * 32 + mi * 16 + ri;
        float4 a0 = *(const float4*)&s_[row][k0p];
        float4 a1 = *(const float4*)&s_[row][k0p + 4];
        bf16x8 afr;
        afr[0] = (bf16_t)a0.x; afr[1] = (bf16_t)a0.y; afr[2] = (bf16_t)a0.z; afr[3] = (bf16_t)a0.w;
        afr[4] = (bf16_t)a1.x; afr[5] = (bf16_t)a1.y; afr[6] = (bf16_t)a1.z; afr[7] = (bf16_t)a1.w;
#pragma unroll
        for (int ni = 0; ni < 4; ++ni)
          acc[mi][ni] = __builtin_amdgcn_mfma_f32_16x16x32_bf16(afr, bfr[ks][ni], acc[mi][ni], 0, 0, 0);
      }
    }

    float cmax[4];
#pragma unroll
    for (int ni = 0; ni < 4; ++ni) {
      float bl = sb[(wn * 4 + ni) * 16 + ri];
      float m = -1e30f;
#pragma unroll
      for (int mi = 0; mi < 2; ++mi) {
        f32x4 a = acc[mi][ni];
        m = fmaxf(m, fmaxf(fmaxf(a.x + szs[mi][0] * bl, a.y + szs[mi][1] * bl),
                           fmaxf(a.z + szs[mi][2] * bl, a.w + szs[mi][3] * bl)));
      }
      cmax[ni] = m;
    }
#pragma unroll
    for (int off = 16; off < 64; off <<= 1) {
#pragma unroll
      for (int ni = 0; ni < 4; ++ni)
        cmax[ni] = fmaxf(cmax[ni], __shfl_xor(cmax[ni], off));
    }
    if (lane < 16) {
#pragma unroll
      for (int ni = 0; ni < 4; ++ni) maxbuf[wm][(wn * 4 + ni) * 16 + lane] = cmax[ni];
    }
    ldsbar();
    if (tid < 128) {
      encodes[(size_t)tree * ENC + tid] = fmaxf(maxbuf[0][tid], maxbuf[1][tid]);
    }
  }
}

// ---------------- K2: GI(bf16) = x @ Wi^T + bi for both directions --------------------
__global__ __launch_bounds__(256) void k2_gi(const float* __restrict__ encodes,
                                             const bf16_t* __restrict__ Wibf,
                                             const float* __restrict__ bi_f,
                                             const float* __restrict__ bi_b,
                                             bf16_t* __restrict__ GIb) {
  int tid = threadIdx.x;
  int wave = tid >> 6;
  int lane = tid & 63;
  int ri = lane & 15;
  int kg = lane >> 4;
  int m0 = blockIdx.x * 16;

  f32x4 acc[10];
#pragma unroll
  for (int i = 0; i < 10; ++i) {
    f32x4 z = {0.f, 0.f, 0.f, 0.f};
    acc[i] = z;
  }

  int r = m0 + ri;
  int er = (r & 127) * 64 + (r >> 7);
  const float* arow = encodes + (size_t)er * ENC;
#pragma unroll
  for (int ks = 0; ks < 4; ++ks) {
    int k0 = ks * 32 + kg * 8;
    float4 a0 = *(const float4*)(arow + k0);
    float4 a1 = *(const float4*)(arow + k0 + 4);
    bf16x8 afr;
    afr[0] = (bf16_t)a0.x; afr[1] = (bf16_t)a0.y; afr[2] = (bf16_t)a0.z; afr[3] = (bf16_t)a0.w;
    afr[4] = (bf16_t)a1.x; afr[5] = (bf16_t)a1.y; afr[6] = (bf16_t)a1.z; afr[7] = (bf16_t)a1.w;
#pragma unroll
    for (int i = 0; i < 10; ++i) {
      int nt = wave + i * 4;
      if (nt < 38) {
        bf16x8 bfr = *(const bf16x8*)(Wibf + (nt * 16 + ri) * 128 + k0);
        acc[i] = __builtin_amdgcn_mfma_f32_16x16x32_bf16(afr, bfr, acc[i], 0, 0, 0);
      }
    }
  }
#pragma unroll
  for (int i = 0; i < 10; ++i) {
    int nt = wave + i * 4;
    if (nt >= 38) continue;
    int jg = nt * 16 + ri;
    int dir = (jg >= GSTRIDE) ? 1 : 0;
    int j = jg - dir * GSTRIDE;
    if (j >= G3) continue;
    float bias = dir ? bi_b[j] : bi_f[j];
#pragma unroll
    for (int rr = 0; rr < 4; ++rr) {
      int rowg = m0 + kg * 4 + rr;
      int l = rowg >> 7, b = rowg & 127;
      GIb[(((size_t)dir * LL + l) * BB + b) * GSTRIDE + j] = (bf16_t)(acc[i][rr] + bias);
    }
  }
}

// ---------------- K3 v3: one barrier/step. 8 threads per j (block 832 = 13 waves).
// sub=tid&7: g=sub>>1 in {r,z,n}, half=sub&1 -> 52-FMA half-dot in registers;
// shfl_xor(1) merges halves; shfl_xor(2)/(4) deliver gh_z/gh_n to gate lane (sub==0).
// h double-buffered in LDS; gi prefetched to regs; gh never touches LDS. ---------------
__global__ __launch_bounds__(832) void k3_gru(const bf16_t* __restrict__ GIb,
                                              const float* __restrict__ Wh_f,
                                              const float* __restrict__ Wh_b,
                                              const float* __restrict__ bh_f,
                                              const float* __restrict__ bh_b,
                                              float* __restrict__ pooled) {
  int blk = blockIdx.x;
  int dir = blk >> 7;
  int b = blk & 127;
  int tid = threadIdx.x;
  __shared__ __align__(16) float h_lds[2][104];
  int j = tid >> 3;
  int sub = tid & 7;
  int g = sub >> 1;
  int half = sub & 1;
  bool isdot = (sub < 6) && (j < HH);
  bool isgate = (sub == 0) && (j < HH);
  const float* Wh = dir ? Wh_b : Wh_f;
  const float* bh = dir ? bh_b : bh_f;

  // Wh row (g*100+j), k-half in registers: 13 float4 (52 floats), zero-pad k>=100
  float4 wv[13];
  if (isdot) {
    const float4* wrow = (const float4*)(Wh + (size_t)(g * HH + j) * HH + half * 52);
#pragma unroll
    for (int c = 0; c < 13; ++c) wv[c] = wrow[c];
    if (half) { float4 z = {0.f, 0.f, 0.f, 0.f}; wv[12] = z; }   // k=100..103 pad
  }
  if (tid < 104) { h_lds[0][tid] = 0.f; h_lds[1][tid] = 0.f; }

  float bhr = 0.f, bhz = 0.f, bhn = 0.f;
  float gir = 0.f, giz = 0.f, gin = 0.f;
  const bf16_t* gbase = nullptr;
  if (isgate) {
    bhr = bh[j]; bhz = bh[HH + j]; bhn = bh[2 * HH + j];
    gbase = GIb + (size_t)dir * LL * BB * GSTRIDE + (size_t)b * GSTRIDE + j;
    int la0 = dir ? 63 : 0;
    const bf16_t* p0 = gbase + (size_t)la0 * BB * GSTRIDE;
    gir = (float)p0[0]; giz = (float)p0[100]; gin = (float)p0[200];
  }
  float h_prev = 0.f, ymax = -1e30f;
  __syncthreads();

  int cur = 0;
  for (int step = 0; step < 64; ++step) {
    // prefetch next step's gi (rides through ldsbar, used next iteration)
    float gnr = 0.f, gnz = 0.f, gnn = 0.f;
    if (isgate && step < 63) {
      int la = dir ? (62 - step) : (step + 1);
      const bf16_t* p = gbase + (size_t)la * BB * GSTRIDE;
      gnr = (float)p[0]; gnz = (float)p[100]; gnn = (float)p[200];
    }
    // half-dot + shuffle delivery (all lanes execute shfls; inactive contribute 0)
    float p = 0.f;
    if (isdot) {
      float a0 = 0.f, a1 = 0.f, a2 = 0.f, a3 = 0.f;
      const float* hb = &h_lds[cur][half * 52];
#pragma unroll
      for (int c = 0; c < 13; ++c) {
        float4 hv = *(const float4*)(hb + c * 4);
        a0 += wv[c].x * hv.x;
        a1 += wv[c].y * hv.y;
        a2 += wv[c].z * hv.z;
        a3 += wv[c].w * hv.w;
      }
      p = (a0 + a1) + (a2 + a3);
    }
    p += __shfl_xor(p, 1);            // merge k-halves
    float gh2 = __shfl_xor(p, 2);     // sub0 <- sub2 (z)
    float gh4 = __shfl_xor(p, 4);     // sub0 <- sub4 (n)
    if (isgate) {
      float r = sigm(gir + p + bhr);
      float z = sigm(giz + gh2 + bhz);
      float n = tanh_f(gin + r * (gh4 + bhn));
      float hnew = (1.f - z) * n + z * h_prev;
      ymax = fmaxf(ymax, hnew);
      h_lds[cur ^ 1][j] = hnew;
      h_prev = hnew;
      gir = gnr; giz = gnz; gin = gnn;
    }
    ldsbar();
    cur ^= 1;
  }
  if (isgate) pooled[(size_t)b * 200 + dir * HH + j] = ymax;
}

// ---------------- K4: final FC ---------------------------------------------------------
__global__ __launch_bounds__(128) void k4_fc(const float* __restrict__ pooled,
                                             const float* __restrict__ W_fc,
                                             const float* __restrict__ b_fc,
                                             float* __restrict__ out) {
  int b = blockIdx.x;
  int o = threadIdx.x;
  if (o >= OUTD) return;
  const float* p = pooled + (size_t)b * 200;
  const float* w = W_fc + (size_t)o * 200;
  float acc = b_fc[o];
#pragma unroll 8
  for (int j = 0; j < 200; ++j) acc += p[j] * w[j];
  out[(size_t)b * OUTD + o] = acc;
}

extern "C" void kernel_launch(void* const* d_in, const int* in_sizes, int n_in,
                              void* d_out, int out_size, void* d_ws, size_t ws_size,
                              hipStream_t stream) {
  const int* tokens = (const int*)d_in[0];
  const float* emb = (const float*)d_in[4];
  const float* W_lin = (const float*)d_in[5];
  const float* b_lin = (const float*)d_in[6];
  const float* Wi_f = (const float*)d_in[7];
  const float* Wh_f = (const float*)d_in[8];
  const float* bi_f = (const float*)d_in[9];
  const float* bh_f = (const float*)d_in[10];
  const float* Wi_b = (const float*)d_in[11];
  const float* Wh_b = (const float*)d_in[12];
  const float* bi_b = (const float*)d_in[13];
  const float* bh_b = (const float*)d_in[14];
  const float* W_fc = (const float*)d_in[15];
  const float* b_fc = (const float*)d_in[16];

  float* encodes = (float*)d_ws;                          // 8192*128 f32 (4MB)
  float* GIreg = encodes + (size_t)TREES * ENC;           // 19.9MB region (shared)
  float* pooled = GIreg + (size_t)2 * LL * BB * GSTRIDE;  // 128*200 f32
  bf16_t* Wbf = (bf16_t*)(pooled + (size_t)BB * 200);     // 128*128 bf16
  bf16_t* Wibf = Wbf + 128 * 128;                         // 608*128 bf16
  // region sharing (stream-ordered): k0 writes embbf -> k1 reads embbf ->
  // k2 overwrites same region as GIb(bf16, 10MB) -> k3 reads GIb.
  bf16_t* embbf = (bf16_t*)GIreg;                         // 50000*128 bf16 (12.8MB)
  bf16_t* GIb = (bf16_t*)GIreg;                           // 2*64*128*304 bf16 (10MB)

  k0_prep<<<2048, 256, 0, stream>>>(W_lin, Wi_f, Wi_b, emb, Wbf, Wibf, embbf);
  k1_tree<<<TREES / TPB_TREES, 256, 0, stream>>>(tokens, embbf, Wbf, b_lin, encodes);
  k2_gi<<<512, 256, 0, stream>>>(encodes, Wibf, bi_f, bi_b, GIb);
  k3_gru<<<256, 832, 0, stream>>>(GIb, Wh_f, Wh_b, bh_f, bh_b, pooled);
  k4_fc<<<BB, 128, 0, stream>>>(pooled, W_fc, b_fc, (float*)d_out);
}

// Round 12
// 178.448 us; speedup vs baseline: 1.0502x; 1.0502x over previous
//
#include <hip/hip_runtime.h>
#include <hip/hip_bf16.h>

typedef __bf16 bf16_t;
typedef __attribute__((ext_vector_type(8))) __bf16 bf16x8;
typedef __attribute__((ext_vector_type(4))) float f32x4;

#define TREES 8192
#define ENC 128
#define HH 100
#define G3 300
#define GSTRIDE 304
#define BB 128
#define LL 64
#define OUTD 104
#define TPB_TREES 8

__device__ __forceinline__ float sigm(float x) { return 1.0f / (1.0f + __expf(-x)); }
__device__ __forceinline__ float tanh_f(float x) { return 2.0f / (1.0f + __expf(-2.0f * x)) - 1.0f; }
__device__ __forceinline__ float bflo(unsigned int u) { return __builtin_bit_cast(float, u << 16); }
__device__ __forceinline__ float bfhi(unsigned int u) { return __builtin_bit_cast(float, u & 0xffff0000u); }

// LDS barrier WITHOUT vmcnt drain: waits LDS ops only, leaves global prefetch in flight.
__device__ __forceinline__ void ldsbar() {
  asm volatile("s_waitcnt lgkmcnt(0)\n\ts_barrier" ::: "memory");
}

// subtree size of node n in the 64-node complete binary tree
__device__ __forceinline__ int subtree_size(int n) {
  int np1 = n + 1;
  int d = 31 - __clz(np1);
  return ((64 >> d) - 1) + (((np1 & (np1 - 1)) == 0) ? 1 : 0);
}

// ---------------- K0: weights->bf16 + emb->bf16 table (grid-stride) --------------------
__global__ __launch_bounds__(256) void k0_prep(const float* __restrict__ W_lin,
                                               const float* __restrict__ Wi_f,
                                               const float* __restrict__ Wi_b,
                                               const float* __restrict__ emb,
                                               bf16_t* __restrict__ Wbf,
                                               bf16_t* __restrict__ Wibf,
                                               bf16_t* __restrict__ embbf) {
  int i = blockIdx.x * 256 + threadIdx.x;      // 0..524287
#pragma unroll
  for (int r = 0; r < 4; ++r) {
    int e = i + r * 524288;
    if (e < 1600000) {                         // 50000*128/4 float4's
      float4 v = ((const float4*)emb)[e];
      ushort4 u;
      u.x = __builtin_bit_cast(unsigned short, (bf16_t)v.x);
      u.y = __builtin_bit_cast(unsigned short, (bf16_t)v.y);
      u.z = __builtin_bit_cast(unsigned short, (bf16_t)v.z);
      u.w = __builtin_bit_cast(unsigned short, (bf16_t)v.w);
      ((ushort4*)embbf)[e] = u;
    }
  }
  if (i < 128 * 128) Wbf[i] = (bf16_t)W_lin[i];
  if (i < 608 * 128) {
    int jg = i >> 7, k = i & 127;
    int dir = (jg >= GSTRIDE) ? 1 : 0;
    int j = jg - dir * GSTRIDE;
    float v = 0.0f;
    if (j < G3) v = dir ? Wi_b[j * 128 + k] : Wi_f[j * 128 + k];
    Wibf[i] = (bf16_t)v;
  }
}

// ---------------- K1 v8 (best-known): swizzled LDS, non-draining barriers,
//                  3-barrier register-chained tree-sum, cross-barrier prefetch. ---------
__global__ __launch_bounds__(256) void k1_tree(const int* __restrict__ tokens,
                                               const bf16_t* __restrict__ embbf,
                                               const bf16_t* __restrict__ Wbf,
                                               const float* __restrict__ b_lin,
                                               float* __restrict__ encodes) {
  __shared__ float s_[64][129];
  __shared__ float maxbuf[2][128];
  __shared__ float sb[128];
  int tid = threadIdx.x;
  int wave = tid >> 6;
  int lane = tid & 63;
  int ri = lane & 15;
  int kg = lane >> 4;
  int wm = wave >> 1;
  int wn = wave & 1;

  if (tid < 128) sb[tid] = b_lin[tid];

  bf16x8 bfr[4][4];
#pragma unroll
  for (int ks = 0; ks < 4; ++ks)
#pragma unroll
    for (int ni = 0; ni < 4; ++ni)
      bfr[ks][ni] = *(const bf16x8*)(Wbf + (size_t)((wn * 4 + ni) * 16 + ri) * 128 +
                                     ks * 32 + kg * 8);

  float szs[2][4];
#pragma unroll
  for (int mi = 0; mi < 2; ++mi)
#pragma unroll
    for (int rr = 0; rr < 4; ++rr)
      szs[mi][rr] = (float)subtree_size(wm * 32 + mi * 16 + kg * 4 + rr);

  int n = tid >> 2;
  int q = tid & 3;
  int c = tid >> 1;
  int half = tid & 1;
  int pc = (c & ~31) | ((((c >> 3) + (c >> 5)) & 3) << 3) | (c & 7);
  int tree0 = blockIdx.x * TPB_TREES;

  uint4 pre[4];
  {
    int tok = tokens[tree0 * 64 + n];
    const uint4* src = (const uint4*)(embbf + (size_t)tok * ENC) + q * 4;
#pragma unroll
    for (int i = 0; i < 4; ++i) pre[i] = src[i];
  }
  __syncthreads();

  for (int t = 0; t < TPB_TREES; ++t) {
    int tree = tree0 + t;

#pragma unroll
    for (int i = 0; i < 4; ++i) {
      uint4 p = pre[i];
      float4 f0 = {bflo(p.x), bfhi(p.x), bflo(p.y), bfhi(p.y)};
      float4 f1 = {bflo(p.z), bfhi(p.z), bflo(p.w), bfhi(p.w)};
      int col = q * 32 + (((i + q) & 3) << 3);
      *(float4*)&s_[n][col] = f0;
      *(float4*)&s_[n][col + 4] = f1;
    }

    if (t + 1 < TPB_TREES) {
      int tok = tokens[(tree + 1) * 64 + n];
      const uint4* src = (const uint4*)(embbf + (size_t)tok * ENC) + q * 4;
#pragma unroll
      for (int i = 0; i < 4; ++i) pre[i] = src[i];
    }
    ldsbar();

    if (half == 0) s_[31][pc] += s_[63][pc];
    {
      float r[8];
      int pb = 15 + half * 8;
#pragma unroll
      for (int i = 0; i < 8; ++i) {
        int p = pb + i;
        r[i] = s_[p][pc] + s_[2 * p + 1][pc] + s_[2 * p + 2][pc];
        s_[p][pc] = r[i];
      }
      float tt[4];
      int pb2 = 7 + half * 4;
#pragma unroll
      for (int i = 0; i < 4; ++i) {
        int p = pb2 + i;
        tt[i] = s_[p][pc] + r[2 * i] + r[2 * i + 1];
        s_[p][pc] = tt[i];
      }
      float uu[2];
      int pb3 = 3 + half * 2;
#pragma unroll
      for (int i = 0; i < 2; ++i) {
        int p = pb3 + i;
        uu[i] = s_[p][pc] + tt[2 * i] + tt[2 * i + 1];
        s_[p][pc] = uu[i];
      }
      int p1 = 1 + half;
      float w1 = s_[p1][pc] + uu[0] + uu[1];
      s_[p1][pc] = w1;
      float w2 = __shfl_xor(w1, 1);
      if (half == 0) s_[0][pc] = s_[0][pc] + w1 + w2;
    }
    ldsbar();

    f32x4 acc[2][4];
#pragma unroll
    for (int mi = 0; mi < 2; ++mi)
#pragma unroll
      for (int ni = 0; ni < 4; ++ni) {
        f32x4 z = {0.f, 0.f, 0.f, 0.f};
        acc[mi][ni] = z;
      }
#pragma unroll
    for (int ks = 0; ks < 4; ++ks) {
      int k0p = ks * 32 + (((kg + ks) & 3) << 3);
#pragma unroll
      for (int mi = 0; mi < 2; ++mi) {
        int row = wm * 32 + mi * 16 + ri;
        float4 a0 = *(const float4*)&s_[row][k0p];
        float4 a1 = *(const float4*)&s_[row][k0p + 4];
        bf16x8 afr;
        afr[0] = (bf16_t)a0.x; afr[1] = (bf16_t)a0.y; afr[2] = (bf16_t)a0.z; afr[3] = (bf16_t)a0.w;
        afr[4] = (bf16_t)a1.x; afr[5] = (bf16_t)a1.y; afr[6] = (bf16_t)a1.z; afr[7] = (bf16_t)a1.w;
#pragma unroll
        for (int ni = 0; ni < 4; ++ni)
          acc[mi][ni] = __builtin_amdgcn_mfma_f32_16x16x32_bf16(afr, bfr[ks][ni], acc[mi][ni], 0, 0, 0);
      }
    }

    float cmax[4];
#pragma unroll
    for (int ni = 0; ni < 4; ++ni) {
      float bl = sb[(wn * 4 + ni) * 16 + ri];
      float m = -1e30f;
#pragma unroll
      for (int mi = 0; mi < 2; ++mi) {
        f32x4 a = acc[mi][ni];
        m = fmaxf(m, fmaxf(fmaxf(a.x + szs[mi][0] * bl, a.y + szs[mi][1] * bl),
                           fmaxf(a.z + szs[mi][2] * bl, a.w + szs[mi][3] * bl)));
      }
      cmax[ni] = m;
    }
#pragma unroll
    for (int off = 16; off < 64; off <<= 1) {
#pragma unroll
      for (int ni = 0; ni < 4; ++ni)
        cmax[ni] = fmaxf(cmax[ni], __shfl_xor(cmax[ni], off));
    }
    if (lane < 16) {
#pragma unroll
      for (int ni = 0; ni < 4; ++ni) maxbuf[wm][(wn * 4 + ni) * 16 + lane] = cmax[ni];
    }
    ldsbar();
    if (tid < 128) {
      encodes[(size_t)tree * ENC + tid] = fmaxf(maxbuf[0][tid], maxbuf[1][tid]);
    }
  }
}

// ---------------- K2: GI(bf16) = x @ Wi^T + bi for both directions --------------------
__global__ __launch_bounds__(256) void k2_gi(const float* __restrict__ encodes,
                                             const bf16_t* __restrict__ Wibf,
                                             const float* __restrict__ bi_f,
                                             const float* __restrict__ bi_b,
                                             bf16_t* __restrict__ GIb) {
  int tid = threadIdx.x;
  int wave = tid >> 6;
  int lane = tid & 63;
  int ri = lane & 15;
  int kg = lane >> 4;
  int m0 = blockIdx.x * 16;

  f32x4 acc[10];
#pragma unroll
  for (int i = 0; i < 10; ++i) {
    f32x4 z = {0.f, 0.f, 0.f, 0.f};
    acc[i] = z;
  }

  int r = m0 + ri;
  int er = (r & 127) * 64 + (r >> 7);
  const float* arow = encodes + (size_t)er * ENC;
#pragma unroll
  for (int ks = 0; ks < 4; ++ks) {
    int k0 = ks * 32 + kg * 8;
    float4 a0 = *(const float4*)(arow + k0);
    float4 a1 = *(const float4*)(arow + k0 + 4);
    bf16x8 afr;
    afr[0] = (bf16_t)a0.x; afr[1] = (bf16_t)a0.y; afr[2] = (bf16_t)a0.z; afr[3] = (bf16_t)a0.w;
    afr[4] = (bf16_t)a1.x; afr[5] = (bf16_t)a1.y; afr[6] = (bf16_t)a1.z; afr[7] = (bf16_t)a1.w;
#pragma unroll
    for (int i = 0; i < 10; ++i) {
      int nt = wave + i * 4;
      if (nt < 38) {
        bf16x8 bfr = *(const bf16x8*)(Wibf + (nt * 16 + ri) * 128 + k0);
        acc[i] = __builtin_amdgcn_mfma_f32_16x16x32_bf16(afr, bfr, acc[i], 0, 0, 0);
      }
    }
  }
#pragma unroll
  for (int i = 0; i < 10; ++i) {
    int nt = wave + i * 4;
    if (nt >= 38) continue;
    int jg = nt * 16 + ri;
    int dir = (jg >= GSTRIDE) ? 1 : 0;
    int j = jg - dir * GSTRIDE;
    if (j >= G3) continue;
    float bias = dir ? bi_b[j] : bi_f[j];
#pragma unroll
    for (int rr = 0; rr < 4; ++rr) {
      int rowg = m0 + kg * 4 + rr;
      int l = rowg >> 7, b = rowg & 127;
      GIb[(((size_t)dir * LL + l) * BB + b) * GSTRIDE + j] = (bf16_t)(acc[i][rr] + bias);
    }
  }
}

// ---------------- K3 v4: 4 rows per thread — LDS h-traffic cut 3.7x --------------------
// 320 threads: jg=tid>>2 (<75), ksub=tid&3. Thread computes 4 outputs jg*4..+3 over
// k-slice {0:28, 28:24, 52:24, 76:24} (16B-aligned). h read ONCE per thread (7 b128),
// 112 FMAs, 2-round shfl_xor(1,2) butterfly merges ksub partials, one write to gh_lds.
// Gate phase (tid<100) + double-buffered gi prefetch = v2 known-good; ldsbar barriers.
__global__ __launch_bounds__(320) void k3_gru(const bf16_t* __restrict__ GIb,
                                              const float* __restrict__ Wh_f,
                                              const float* __restrict__ Wh_b,
                                              const float* __restrict__ bh_f,
                                              const float* __restrict__ bh_b,
                                              float* __restrict__ pooled) {
  int blk = blockIdx.x;
  int dir = blk >> 7;
  int b = blk & 127;
  int tid = threadIdx.x;
  __shared__ __align__(16) float h_lds[112];     // 100 live + zero pad
  __shared__ float gh_lds[304];
  __shared__ float gi_lds[2][304];
  const float* Wh = dir ? Wh_b : Wh_f;
  const float* bh = dir ? bh_b : bh_f;

  int jg = tid >> 2;
  int ksub = tid & 3;
  bool isdot = (jg < 75);
  int koff = (ksub == 0) ? 0 : (4 + ksub * 24);  // 0,28,52,76
  int kn = (ksub == 0) ? 28 : 24;

  // weights: 4 rows x 28 k's in registers (zero-padded), static indices only
  float4 wv[4][7];
#pragma unroll
  for (int r = 0; r < 4; ++r)
#pragma unroll
    for (int c7 = 0; c7 < 7; ++c7) {
      float4 v = {0.f, 0.f, 0.f, 0.f};
      if (isdot) {
        const float* wrow = Wh + (size_t)(jg * 4 + r) * HH + koff;
        int c0 = c7 * 4;
        if (c0 + 0 < kn) v.x = wrow[c0 + 0];
        if (c0 + 1 < kn) v.y = wrow[c0 + 1];
        if (c0 + 2 < kn) v.z = wrow[c0 + 2];
        if (c0 + 3 < kn) v.w = wrow[c0 + 3];
      }
      wv[r][c7] = v;
    }

  if (tid < 112) h_lds[tid] = 0.f;

  float bhr = 0.f, bhz = 0.f, bhn = 0.f;
  if (tid < HH) { bhr = bh[tid]; bhz = bh[HH + tid]; bhn = bh[2 * HH + tid]; }

  const bf16_t* giB = GIb + (size_t)dir * LL * BB * GSTRIDE + (size_t)b * GSTRIDE;
  if (tid < G3) {
    int la0 = dir ? 63 : 0;
    gi_lds[0][tid] = (float)giB[(size_t)la0 * BB * GSTRIDE + tid];
  }
  float ymax = -1e30f;
  __syncthreads();

  int cur = 0;
  for (int step = 0; step < 64; ++step) {
    int nxt = cur ^ 1;
    // prefetch next step's gi (rides through ldsbar — no vmcnt drain)
    float ginext = 0.f;
    if (tid < G3 && step < 63) {
      int la = dir ? (62 - step) : (step + 1);
      ginext = (float)giB[(size_t)la * BB * GSTRIDE + tid];
    }
    // dot: 4 rows x 28 k's on one h-slice read
    f32x4 facc = {0.f, 0.f, 0.f, 0.f};
    if (isdot) {
      float4 hv[7];
#pragma unroll
      for (int c7 = 0; c7 < 7; ++c7) hv[c7] = *(const float4*)&h_lds[koff + c7 * 4];
      float a0 = 0.f, a1 = 0.f, a2 = 0.f, a3 = 0.f;
#pragma unroll
      for (int c7 = 0; c7 < 7; ++c7) {
        a0 += wv[0][c7].x * hv[c7].x + wv[0][c7].y * hv[c7].y +
              wv[0][c7].z * hv[c7].z + wv[0][c7].w * hv[c7].w;
        a1 += wv[1][c7].x * hv[c7].x + wv[1][c7].y * hv[c7].y +
              wv[1][c7].z * hv[c7].z + wv[1][c7].w * hv[c7].w;
        a2 += wv[2][c7].x * hv[c7].x + wv[2][c7].y * hv[c7].y +
              wv[2][c7].z * hv[c7].z + wv[2][c7].w * hv[c7].w;
        a3 += wv[3][c7].x * hv[c7].x + wv[3][c7].y * hv[c7].y +
              wv[3][c7].z * hv[c7].z + wv[3][c7].w * hv[c7].w;
      }
      facc[0] = a0; facc[1] = a1; facc[2] = a2; facc[3] = a3;
    }
    // butterfly over the 4-lane ksub group (all lanes participate)
#pragma unroll
    for (int e = 0; e < 4; ++e) facc[e] += __shfl_xor(facc[e], 1);
#pragma unroll
    for (int e = 0; e < 4; ++e) facc[e] += __shfl_xor(facc[e], 2);
    if (isdot) {
      float out = (ksub == 0) ? facc[0] : (ksub == 1) ? facc[1]
                : (ksub == 2) ? facc[2] : facc[3];
      gh_lds[jg * 4 + ksub] = out;
    }
    ldsbar();
    // gates
    if (tid < HH) {
      float r = sigm(gi_lds[cur][tid] + gh_lds[tid] + bhr);
      float z = sigm(gi_lds[cur][100 + tid] + gh_lds[100 + tid] + bhz);
      float n = tanh_f(gi_lds[cur][200 + tid] + r * (gh_lds[200 + tid] + bhn));
      float hnew = (1.f - z) * n + z * h_lds[tid];
      ymax = fmaxf(ymax, hnew);
      h_lds[tid] = hnew;
    }
    if (tid < G3 && step < 63) gi_lds[nxt][tid] = ginext;
    ldsbar();
    cur = nxt;
  }
  if (tid < HH) pooled[(size_t)b * 200 + dir * HH + tid] = ymax;
}

// ---------------- K4: final FC ---------------------------------------------------------
__global__ __launch_bounds__(128) void k4_fc(const float* __restrict__ pooled,
                                             const float* __restrict__ W_fc,
                                             const float* __restrict__ b_fc,
                                             float* __restrict__ out) {
  int b = blockIdx.x;
  int o = threadIdx.x;
  if (o >= OUTD) return;
  const float* p = pooled + (size_t)b * 200;
  const float* w = W_fc + (size_t)o * 200;
  float acc = b_fc[o];
#pragma unroll 8
  for (int j = 0; j < 200; ++j) acc += p[j] * w[j];
  out[(size_t)b * OUTD + o] = acc;
}

extern "C" void kernel_launch(void* const* d_in, const int* in_sizes, int n_in,
                              void* d_out, int out_size, void* d_ws, size_t ws_size,
                              hipStream_t stream) {
  const int* tokens = (const int*)d_in[0];
  const float* emb = (const float*)d_in[4];
  const float* W_lin = (const float*)d_in[5];
  const float* b_lin = (const float*)d_in[6];
  const float* Wi_f = (const float*)d_in[7];
  const float* Wh_f = (const float*)d_in[8];
  const float* bi_f = (const float*)d_in[9];
  const float* bh_f = (const float*)d_in[10];
  const float* Wi_b = (const float*)d_in[11];
  const float* Wh_b = (const float*)d_in[12];
  const float* bi_b = (const float*)d_in[13];
  const float* bh_b = (const float*)d_in[14];
  const float* W_fc = (const float*)d_in[15];
  const float* b_fc = (const float*)d_in[16];

  float* encodes = (float*)d_ws;                          // 8192*128 f32 (4MB)
  float* GIreg = encodes + (size_t)TREES * ENC;           // 19.9MB region (shared)
  float* pooled = GIreg + (size_t)2 * LL * BB * GSTRIDE;  // 128*200 f32
  bf16_t* Wbf = (bf16_t*)(pooled + (size_t)BB * 200);     // 128*128 bf16
  bf16_t* Wibf = Wbf + 128 * 128;                         // 608*128 bf16
  // region sharing (stream-ordered): k0 writes embbf -> k1 reads embbf ->
  // k2 overwrites same region as GIb(bf16, 10MB) -> k3 reads GIb.
  bf16_t* embbf = (bf16_t*)GIreg;                         // 50000*128 bf16 (12.8MB)
  bf16_t* GIb = (bf16_t*)GIreg;                           // 2*64*128*304 bf16 (10MB)

  k0_prep<<<2048, 256, 0, stream>>>(W_lin, Wi_f, Wi_b, emb, Wbf, Wibf, embbf);
  k1_tree<<<TREES / TPB_TREES, 256, 0, stream>>>(tokens, embbf, Wbf, b_lin, encodes);
  k2_gi<<<512, 256, 0, stream>>>(encodes, Wibf, bi_f, bi_b, GIb);
  k3_gru<<<256, 320, 0, stream>>>(GIb, Wh_f, Wh_b, bh_f, bh_b, pooled);
  k4_fc<<<BB, 128, 0, stream>>>(pooled, W_fc, b_fc, (float*)d_out);
}

// Round 13
// 142.876 us; speedup vs baseline: 1.3117x; 1.2490x over previous
//
#include <hip/hip_runtime.h>
#include <hip/hip_bf16.h>

typedef __bf16 bf16_t;
typedef __attribute__((ext_vector_type(8))) __bf16 bf16x8;
typedef __attribute__((ext_vector_type(4))) float f32x4;

#define TREES 8192
#define ENC 128
#define HH 100
#define G3 300
#define GSTRIDE 304
#define BB 128
#define LL 64
#define OUTD 104
#define TPB_TREES 8

__device__ __forceinline__ float sigm(float x) { return 1.0f / (1.0f + __expf(-x)); }
__device__ __forceinline__ float tanh_f(float x) { return 2.0f / (1.0f + __expf(-2.0f * x)) - 1.0f; }
__device__ __forceinline__ float bflo(unsigned int u) { return __builtin_bit_cast(float, u << 16); }
__device__ __forceinline__ float bfhi(unsigned int u) { return __builtin_bit_cast(float, u & 0xffff0000u); }

// LDS barrier WITHOUT vmcnt drain: waits LDS ops only, leaves global prefetch in flight.
__device__ __forceinline__ void ldsbar() {
  asm volatile("s_waitcnt lgkmcnt(0)\n\ts_barrier" ::: "memory");
}

// subtree size of node n in the 64-node complete binary tree
__device__ __forceinline__ int subtree_size(int n) {
  int np1 = n + 1;
  int d = 31 - __clz(np1);
  return ((64 >> d) - 1) + (((np1 & (np1 - 1)) == 0) ? 1 : 0);
}

// ---------------- K0: weights->bf16 + emb->bf16 table (grid-stride) --------------------
__global__ __launch_bounds__(256) void k0_prep(const float* __restrict__ W_lin,
                                               const float* __restrict__ Wi_f,
                                               const float* __restrict__ Wi_b,
                                               const float* __restrict__ emb,
                                               bf16_t* __restrict__ Wbf,
                                               bf16_t* __restrict__ Wibf,
                                               bf16_t* __restrict__ embbf) {
  int i = blockIdx.x * 256 + threadIdx.x;      // 0..524287
#pragma unroll
  for (int r = 0; r < 4; ++r) {
    int e = i + r * 524288;
    if (e < 1600000) {                         // 50000*128/4 float4's
      float4 v = ((const float4*)emb)[e];
      ushort4 u;
      u.x = __builtin_bit_cast(unsigned short, (bf16_t)v.x);
      u.y = __builtin_bit_cast(unsigned short, (bf16_t)v.y);
      u.z = __builtin_bit_cast(unsigned short, (bf16_t)v.z);
      u.w = __builtin_bit_cast(unsigned short, (bf16_t)v.w);
      ((ushort4*)embbf)[e] = u;
    }
  }
  if (i < 128 * 128) Wbf[i] = (bf16_t)W_lin[i];
  if (i < 608 * 128) {
    int jg = i >> 7, k = i & 127;
    int dir = (jg >= GSTRIDE) ? 1 : 0;
    int j = jg - dir * GSTRIDE;
    float v = 0.0f;
    if (j < G3) v = dir ? Wi_b[j * 128 + k] : Wi_f[j * 128 + k];
    Wibf[i] = (bf16_t)v;
  }
}

// ---------------- K1 v8 (best-known): swizzled LDS, non-draining barriers,
//                  3-barrier register-chained tree-sum, cross-barrier prefetch. ---------
__global__ __launch_bounds__(256) void k1_tree(const int* __restrict__ tokens,
                                               const bf16_t* __restrict__ embbf,
                                               const bf16_t* __restrict__ Wbf,
                                               const float* __restrict__ b_lin,
                                               float* __restrict__ encodes) {
  __shared__ float s_[64][129];
  __shared__ float maxbuf[2][128];
  __shared__ float sb[128];
  int tid = threadIdx.x;
  int wave = tid >> 6;
  int lane = tid & 63;
  int ri = lane & 15;
  int kg = lane >> 4;
  int wm = wave >> 1;
  int wn = wave & 1;

  if (tid < 128) sb[tid] = b_lin[tid];

  bf16x8 bfr[4][4];
#pragma unroll
  for (int ks = 0; ks < 4; ++ks)
#pragma unroll
    for (int ni = 0; ni < 4; ++ni)
      bfr[ks][ni] = *(const bf16x8*)(Wbf + (size_t)((wn * 4 + ni) * 16 + ri) * 128 +
                                     ks * 32 + kg * 8);

  float szs[2][4];
#pragma unroll
  for (int mi = 0; mi < 2; ++mi)
#pragma unroll
    for (int rr = 0; rr < 4; ++rr)
      szs[mi][rr] = (float)subtree_size(wm * 32 + mi * 16 + kg * 4 + rr);

  int n = tid >> 2;
  int q = tid & 3;
  int c = tid >> 1;
  int half = tid & 1;
  int pc = (c & ~31) | ((((c >> 3) + (c >> 5)) & 3) << 3) | (c & 7);
  int tree0 = blockIdx.x * TPB_TREES;

  uint4 pre[4];
  {
    int tok = tokens[tree0 * 64 + n];
    const uint4* src = (const uint4*)(embbf + (size_t)tok * ENC) + q * 4;
#pragma unroll
    for (int i = 0; i < 4; ++i) pre[i] = src[i];
  }
  __syncthreads();

  for (int t = 0; t < TPB_TREES; ++t) {
    int tree = tree0 + t;

#pragma unroll
    for (int i = 0; i < 4; ++i) {
      uint4 p = pre[i];
      float4 f0 = {bflo(p.x), bfhi(p.x), bflo(p.y), bfhi(p.y)};
      float4 f1 = {bflo(p.z), bfhi(p.z), bflo(p.w), bfhi(p.w)};
      int col = q * 32 + (((i + q) & 3) << 3);
      *(float4*)&s_[n][col] = f0;
      *(float4*)&s_[n][col + 4] = f1;
    }

    if (t + 1 < TPB_TREES) {
      int tok = tokens[(tree + 1) * 64 + n];
      const uint4* src = (const uint4*)(embbf + (size_t)tok * ENC) + q * 4;
#pragma unroll
      for (int i = 0; i < 4; ++i) pre[i] = src[i];
    }
    ldsbar();

    if (half == 0) s_[31][pc] += s_[63][pc];
    {
      float r[8];
      int pb = 15 + half * 8;
#pragma unroll
      for (int i = 0; i < 8; ++i) {
        int p = pb + i;
        r[i] = s_[p][pc] + s_[2 * p + 1][pc] + s_[2 * p + 2][pc];
        s_[p][pc] = r[i];
      }
      float tt[4];
      int pb2 = 7 + half * 4;
#pragma unroll
      for (int i = 0; i < 4; ++i) {
        int p = pb2 + i;
        tt[i] = s_[p][pc] + r[2 * i] + r[2 * i + 1];
        s_[p][pc] = tt[i];
      }
      float uu[2];
      int pb3 = 3 + half * 2;
#pragma unroll
      for (int i = 0; i < 2; ++i) {
        int p = pb3 + i;
        uu[i] = s_[p][pc] + tt[2 * i] + tt[2 * i + 1];
        s_[p][pc] = uu[i];
      }
      int p1 = 1 + half;
      float w1 = s_[p1][pc] + uu[0] + uu[1];
      s_[p1][pc] = w1;
      float w2 = __shfl_xor(w1, 1);
      if (half == 0) s_[0][pc] = s_[0][pc] + w1 + w2;
    }
    ldsbar();

    f32x4 acc[2][4];
#pragma unroll
    for (int mi = 0; mi < 2; ++mi)
#pragma unroll
      for (int ni = 0; ni < 4; ++ni) {
        f32x4 z = {0.f, 0.f, 0.f, 0.f};
        acc[mi][ni] = z;
      }
#pragma unroll
    for (int ks = 0; ks < 4; ++ks) {
      int k0p = ks * 32 + (((kg + ks) & 3) << 3);
#pragma unroll
      for (int mi = 0; mi < 2; ++mi) {
        int row = wm * 32 + mi * 16 + ri;
        float4 a0 = *(const float4*)&s_[row][k0p];
        float4 a1 = *(const float4*)&s_[row][k0p + 4];
        bf16x8 afr;
        afr[0] = (bf16_t)a0.x; afr[1] = (bf16_t)a0.y; afr[2] = (bf16_t)a0.z; afr[3] = (bf16_t)a0.w;
        afr[4] = (bf16_t)a1.x; afr[5] = (bf16_t)a1.y; afr[6] = (bf16_t)a1.z; afr[7] = (bf16_t)a1.w;
#pragma unroll
        for (int ni = 0; ni < 4; ++ni)
          acc[mi][ni] = __builtin_amdgcn_mfma_f32_16x16x32_bf16(afr, bfr[ks][ni], acc[mi][ni], 0, 0, 0);
      }
    }

    float cmax[4];
#pragma unroll
    for (int ni = 0; ni < 4; ++ni) {
      float bl = sb[(wn * 4 + ni) * 16 + ri];
      float m = -1e30f;
#pragma unroll
      for (int mi = 0; mi < 2; ++mi) {
        f32x4 a = acc[mi][ni];
        m = fmaxf(m, fmaxf(fmaxf(a.x + szs[mi][0] * bl, a.y + szs[mi][1] * bl),
                           fmaxf(a.z + szs[mi][2] * bl, a.w + szs[mi][3] * bl)));
      }
      cmax[ni] = m;
    }
#pragma unroll
    for (int off = 16; off < 64; off <<= 1) {
#pragma unroll
      for (int ni = 0; ni < 4; ++ni)
        cmax[ni] = fmaxf(cmax[ni], __shfl_xor(cmax[ni], off));
    }
    if (lane < 16) {
#pragma unroll
      for (int ni = 0; ni < 4; ++ni) maxbuf[wm][(wn * 4 + ni) * 16 + lane] = cmax[ni];
    }
    ldsbar();
    if (tid < 128) {
      encodes[(size_t)tree * ENC + tid] = fmaxf(maxbuf[0][tid], maxbuf[1][tid]);
    }
  }
}

// ---------------- K2: GI(f32) = x @ Wi^T + bi for both directions (R8 exact) ----------
__global__ __launch_bounds__(256) void k2_gi(const float* __restrict__ encodes,
                                             const bf16_t* __restrict__ Wibf,
                                             const float* __restrict__ bi_f,
                                             const float* __restrict__ bi_b,
                                             float* __restrict__ GI) {
  int tid = threadIdx.x;
  int wave = tid >> 6;
  int lane = tid & 63;
  int ri = lane & 15;
  int kg = lane >> 4;
  int m0 = blockIdx.x * 16;

  f32x4 acc[10];
#pragma unroll
  for (int i = 0; i < 10; ++i) {
    f32x4 z = {0.f, 0.f, 0.f, 0.f};
    acc[i] = z;
  }

  int r = m0 + ri;
  int er = (r & 127) * 64 + (r >> 7);
  const float* arow = encodes + (size_t)er * ENC;
#pragma unroll
  for (int ks = 0; ks < 4; ++ks) {
    int k0 = ks * 32 + kg * 8;
    float4 a0 = *(const float4*)(arow + k0);
    float4 a1 = *(const float4*)(arow + k0 + 4);
    bf16x8 afr;
    afr[0] = (bf16_t)a0.x; afr[1] = (bf16_t)a0.y; afr[2] = (bf16_t)a0.z; afr[3] = (bf16_t)a0.w;
    afr[4] = (bf16_t)a1.x; afr[5] = (bf16_t)a1.y; afr[6] = (bf16_t)a1.z; afr[7] = (bf16_t)a1.w;
#pragma unroll
    for (int i = 0; i < 10; ++i) {
      int nt = wave + i * 4;
      if (nt < 38) {
        bf16x8 bfr = *(const bf16x8*)(Wibf + (nt * 16 + ri) * 128 + k0);
        acc[i] = __builtin_amdgcn_mfma_f32_16x16x32_bf16(afr, bfr, acc[i], 0, 0, 0);
      }
    }
  }
#pragma unroll
  for (int i = 0; i < 10; ++i) {
    int nt = wave + i * 4;
    if (nt >= 38) continue;
    int jg = nt * 16 + ri;
    int dir = (jg >= GSTRIDE) ? 1 : 0;
    int j = jg - dir * GSTRIDE;
    if (j >= G3) continue;
    float bias = dir ? bi_b[j] : bi_f[j];
#pragma unroll
    for (int rr = 0; rr < 4; ++rr) {
      int rowg = m0 + kg * 4 + rr;
      int l = rowg >> 7, b = rowg & 127;
      GI[(((size_t)dir * LL + l) * BB + b) * GSTRIDE + j] = acc[i][rr] + bias;
    }
  }
}

// ---------------- K3 v2 (best-known) with non-draining barriers ------------------------
__global__ __launch_bounds__(640) void k3_gru(const float* __restrict__ GI,
                                              const float* __restrict__ Wh_f,
                                              const float* __restrict__ Wh_b,
                                              const float* __restrict__ bh_f,
                                              const float* __restrict__ bh_b,
                                              float* __restrict__ pooled) {
  int blk = blockIdx.x;
  int dir = blk >> 7;
  int b = blk & 127;
  int tid = threadIdx.x;
  __shared__ __align__(16) float h_lds[104];
  __shared__ float gh_lds[304];
  __shared__ float gi_lds[2][304];
  const float* Wh = dir ? Wh_b : Wh_f;
  const float* bh = dir ? bh_b : bh_f;

  int j = tid >> 1;
  int kg = tid & 1;
  int kbase = kg * 52;
  bool isdot = (tid < 600);

  float4 wv[13];
  float bhj = 0.f;
  if (isdot) {
#pragma unroll
    for (int c = 0; c < 13; ++c) {
      int k0 = kbase + c * 4;
      float4 v;
      v.x = (k0 + 0 < HH) ? Wh[j * HH + k0 + 0] : 0.f;
      v.y = (k0 + 1 < HH) ? Wh[j * HH + k0 + 1] : 0.f;
      v.z = (k0 + 2 < HH) ? Wh[j * HH + k0 + 2] : 0.f;
      v.w = (k0 + 3 < HH) ? Wh[j * HH + k0 + 3] : 0.f;
      wv[c] = v;
    }
    if (kg == 0) bhj = bh[j];
  }
  if (tid < 104) h_lds[tid] = 0.f;

  const float* giB = GI + (size_t)dir * LL * BB * GSTRIDE + (size_t)b * GSTRIDE;
  if (tid < G3) {
    int la0 = dir ? 63 : 0;
    gi_lds[0][tid] = giB[(size_t)la0 * BB * GSTRIDE + tid];
  }
  float ymax = -1e30f;
  __syncthreads();

  for (int step = 0; step < 64; ++step) {
    int cur = step & 1;
    int nxt = cur ^ 1;
    float ginext = 0.f;
    if (tid < G3) {
      int ns = (step < 63) ? step + 1 : 63;
      int la = dir ? (63 - ns) : ns;
      ginext = giB[(size_t)la * BB * GSTRIDE + tid];
    }
    if (isdot) {
      float a0 = 0.f, a1 = 0.f, a2 = 0.f, a3 = 0.f;
#pragma unroll
      for (int c = 0; c < 13; ++c) {
        float4 hv = *(const float4*)&h_lds[kbase + c * 4];
        a0 += wv[c].x * hv.x;
        a1 += wv[c].y * hv.y;
        a2 += wv[c].z * hv.z;
        a3 += wv[c].w * hv.w;
      }
      float p = (a0 + a1) + (a2 + a3);
      p += __shfl_xor(p, 1);
      if (kg == 0) gh_lds[j] = p + bhj;
    }
    ldsbar();   // non-draining: gi prefetch rides through
    if (tid < HH) {
      float r = sigm(gi_lds[cur][tid] + gh_lds[tid]);
      float z = sigm(gi_lds[cur][100 + tid] + gh_lds[100 + tid]);
      float n = tanh_f(gi_lds[cur][200 + tid] + r * gh_lds[200 + tid]);
      float hnew = (1.f - z) * n + z * h_lds[tid];
      ymax = fmaxf(ymax, hnew);
      h_lds[tid] = hnew;
    }
    if (tid < G3 && step < 63) gi_lds[nxt][tid] = ginext;
    ldsbar();   // non-draining
  }
  if (tid < HH) pooled[(size_t)b * 200 + dir * 100 + tid] = ymax;
}

// ---------------- K4: final FC ---------------------------------------------------------
__global__ __launch_bounds__(128) void k4_fc(const float* __restrict__ pooled,
                                             const float* __restrict__ W_fc,
                                             const float* __restrict__ b_fc,
                                             float* __restrict__ out) {
  int b = blockIdx.x;
  int o = threadIdx.x;
  if (o >= OUTD) return;
  const float* p = pooled + (size_t)b * 200;
  const float* w = W_fc + (size_t)o * 200;
  float acc = b_fc[o];
#pragma unroll 8
  for (int j = 0; j < 200; ++j) acc += p[j] * w[j];
  out[(size_t)b * OUTD + o] = acc;
}

extern "C" void kernel_launch(void* const* d_in, const int* in_sizes, int n_in,
                              void* d_out, int out_size, void* d_ws, size_t ws_size,
                              hipStream_t stream) {
  const int* tokens = (const int*)d_in[0];
  const float* emb = (const float*)d_in[4];
  const float* W_lin = (const float*)d_in[5];
  const float* b_lin = (const float*)d_in[6];
  const float* Wi_f = (const float*)d_in[7];
  const float* Wh_f = (const float*)d_in[8];
  const float* bi_f = (const float*)d_in[9];
  const float* bh_f = (const float*)d_in[10];
  const float* Wi_b = (const float*)d_in[11];
  const float* Wh_b = (const float*)d_in[12];
  const float* bi_b = (const float*)d_in[13];
  const float* bh_b = (const float*)d_in[14];
  const float* W_fc = (const float*)d_in[15];
  const float* b_fc = (const float*)d_in[16];

  float* encodes = (float*)d_ws;                          // 8192*128 f32 (4MB)
  float* GI = encodes + (size_t)TREES * ENC;              // 2*64*128*304 f32 (19.9MB)
  float* pooled = GI + (size_t)2 * LL * BB * GSTRIDE;     // 128*200 f32
  bf16_t* Wbf = (bf16_t*)(pooled + (size_t)BB * 200);     // 128*128 bf16
  bf16_t* Wibf = Wbf + 128 * 128;                         // 608*128 bf16
  // embbf ALIASES GI region: k0 writes embbf -> k1 reads -> k2 overwrites as GI(f32)
  bf16_t* embbf = (bf16_t*)GI;                            // 50000*128 bf16 (12.8MB < 19.9MB)

  k0_prep<<<2048, 256, 0, stream>>>(W_lin, Wi_f, Wi_b, emb, Wbf, Wibf, embbf);
  k1_tree<<<TREES / TPB_TREES, 256, 0, stream>>>(tokens, embbf, Wbf, b_lin, encodes);
  k2_gi<<<512, 256, 0, stream>>>(encodes, Wibf, bi_f, bi_b, GI);
  k3_gru<<<256, 640, 0, stream>>>(GI, Wh_f, Wh_b, bh_f, bh_b, pooled);
  k4_fc<<<BB, 128, 0, stream>>>(pooled, W_fc, b_fc, (float*)d_out);
}